// Round 15
// baseline (320.955 us; speedup 1.0000x reference)
//
#include <hip/hip_runtime.h>
#include <hip/hip_bf16.h>
#include <hip/hip_fp8.h>
#include <math.h>

#define N_NODES 50000
#define N_EDGES 800000
#define NFEAT 3
#define C1 512
#define C2 256
#define C3 128
#define NGRAPH 100
#define NCLS 2
#define PSPLIT 8
#define NRANGE 8
#define RANGE_SZ 6250  // N_NODES / NRANGE

typedef short bh8 __attribute__((ext_vector_type(8)));   // 8 bf16 bit-patterns (4 VGPRs)
typedef float f32x4 __attribute__((ext_vector_type(4))); // MFMA accumulator

__device__ __forceinline__ short f2bf(float x) {
    __hip_bfloat16 h = __float2bfloat16(x);
    return *reinterpret_cast<short*>(&h);
}
__device__ __forceinline__ float bflo(unsigned int u) { return __uint_as_float(u << 16); }
__device__ __forceinline__ float bfhi(unsigned int u) { return __uint_as_float(u & 0xffff0000u); }
__device__ __forceinline__ unsigned int packbf(float a, float b) {
    return (unsigned int)(unsigned short)f2bf(a) | ((unsigned int)(unsigned short)f2bf(b) << 16);
}
// OCP e4m3 fp8 encode; packed-pair decode (HW v_cvt_pk_f32_fp8 on gfx950)
__device__ __forceinline__ unsigned char f2fp8(float x) {
    __hip_fp8_e4m3 q(x);
    return (unsigned char)q.__x;
}
__device__ __forceinline__ float2 fp8x2(unsigned short u) {
    __hip_fp8x2_e4m3 q; q.__x = u; return (float2)q;
}

// ---------------- degree count, col-range partitioned (XCD-local atomics) ----------------

__global__ void count_edges(const int* __restrict__ col, int* __restrict__ counts) {
    int range = blockIdx.x & (NRANGE - 1);
    int e = (blockIdx.x >> 3) * 256 + threadIdx.x;
    if (e < N_EDGES) {
        int c = col[e];
        int lo = range * RANGE_SZ;
        if (c >= lo && c < lo + RANGE_SZ) atomicAdd(&counts[c], 1);
    }
}

// ------- CSR build: scan (fused dis + packed xd={x,dis}) + partitioned scatter -------

__global__ void scan_chunks(const int* __restrict__ counts, const float* __restrict__ x,
                            int* __restrict__ offsets, int* __restrict__ chunksums,
                            float* __restrict__ dis, float4* __restrict__ xd) {
    __shared__ int s[256];
    int b = blockIdx.x, t = threadIdx.x;
    int i = b * 256 + t;
    int v = (i < N_NODES) ? counts[i] : 0;
    if (i < N_NODES) {
        float d = rsqrtf((float)(v + 1)); // +1 self loop
        dis[i] = d;
        xd[i] = make_float4(x[i * 3 + 0], x[i * 3 + 1], x[i * 3 + 2], d);
    }
    s[t] = v;
    __syncthreads();
    for (int d = 1; d < 256; d <<= 1) {
        int add = (t >= d) ? s[t - d] : 0;
        __syncthreads();
        s[t] += add;
        __syncthreads();
    }
    if (i < N_NODES) offsets[i + 1] = s[t];
    if (t == 255) chunksums[b] = s[255];
}

__global__ void scan_sums(int* __restrict__ chunksums, int nchunks) {
    __shared__ int s[256];
    int t = threadIdx.x;
    int v = (t < nchunks) ? chunksums[t] : 0;
    s[t] = v;
    __syncthreads();
    for (int d = 1; d < 256; d <<= 1) {
        int add = (t >= d) ? s[t - d] : 0;
        __syncthreads();
        s[t] += add;
        __syncthreads();
    }
    if (t < nchunks) chunksums[t] = (t == 0) ? 0 : s[t - 1];
}

// also initializes cursor[] = final offsets (no separate init kernel)
__global__ void finalize_offsets(int* __restrict__ offsets, const int* __restrict__ chunkoffs,
                                 int* __restrict__ cursor) {
    int i = blockIdx.x * blockDim.x + threadIdx.x;
    if (i < N_NODES) {
        int v = offsets[i + 1] + chunkoffs[i / 256];
        offsets[i + 1] = v;
        if (i + 1 < N_NODES) cursor[i + 1] = v;
    }
    if (i == 0) { offsets[0] = 0; cursor[0] = 0; }
}

__global__ void scatter_edges(const int* __restrict__ rowi, const int* __restrict__ coli,
                              int* __restrict__ cursor, int* __restrict__ csr_src) {
    int range = blockIdx.x & (NRANGE - 1);
    int e = (blockIdx.x >> 3) * 256 + threadIdx.x;
    if (e < N_EDGES) {
        int c = coli[e];
        int lo = range * RANGE_SZ;
        if (c >= lo && c < lo + RANGE_SZ) {
            int p = atomicAdd(&cursor[c], 1);
            csr_src[p] = rowi[e];
        }
    }
}

// ---------------- weight transpose + bf16 cast (both layers in one kernel) ----------------

__global__ void prep_weights(const float* __restrict__ W2, const float* __restrict__ W3,
                             short* __restrict__ W2t, short* __restrict__ W3t) {
    int idx = blockIdx.x * 256 + threadIdx.x;
    if (idx < C1 * C2) {
        int n = idx / C1, k = idx % C1;
        W2t[idx] = f2bf(W2[k * C2 + n]);
    } else if (idx < C1 * C2 + C2 * C3) {
        int j = idx - C1 * C2;
        int n = j / C2, k = j % C2;
        W3t[j] = f2bf(W3[k * C3 + n]);
    }
}

// ------- layer-1 feature aggregate: 16 lanes per node, shuffle-reduced -------
// xd[i] = {x0,x1,x2,dis}; aggx[i] = dis_i * ( dis_i*x[i] + sum_r dis_r*x[r] )
// 256-thread block = 16 nodes; lanes stride the edge list (16 gathers in flight/node).

__global__ __launch_bounds__(256) void agg_feat3(const float4* __restrict__ xd,
                                                 const int* __restrict__ offsets,
                                                 const int* __restrict__ csr_src,
                                                 float* __restrict__ aggx) {
    int t = threadIdx.x;
    int l = t & 15;            // lane within 16-lane group
    int i = blockIdx.x * 16 + (t >> 4);
    if (i >= N_NODES) return;
    int s = offsets[i], e = offsets[i + 1];
    float a0 = 0.f, a1 = 0.f, a2 = 0.f;
    for (int p = s + l; p < e; p += 16) {
        int r = csr_src[p];
        float4 v = xd[r];
        a0 += v.w * v.x;
        a1 += v.w * v.y;
        a2 += v.w * v.z;
    }
#pragma unroll
    for (int m = 1; m < 16; m <<= 1) {
        a0 += __shfl_xor(a0, m);
        a1 += __shfl_xor(a1, m);
        a2 += __shfl_xor(a2, m);
    }
    if (l == 0) {
        float4 self = xd[i];
        float di = self.w;
        a0 += di * self.x; a1 += di * self.y; a2 += di * self.z;
        aggx[i * 3 + 0] = di * a0;
        aggx[i * 3 + 1] = di * a1;
        aggx[i * 3 + 2] = di * a2;
    }
}

// ---- FUSED layer1 + GEMM2: m2[M x C2] = (di*relu(aggx@W1+b1)) @ W2t^T, OUTPUT FP8 ----

__global__ __launch_bounds__(512, 4) void gemm_l1(const float* __restrict__ aggx,
                                                  const float* __restrict__ W1,
                                                  const float* __restrict__ b1,
                                                  const float* __restrict__ dis,
                                                  const short* __restrict__ Bt,
                                                  unsigned char* __restrict__ Cmat, int M) {
    __shared__ short As[128 * 32];
    __shared__ short Bs[C2 * 32];
    __shared__ float sW1[3 * C1];
    __shared__ float sb1[C1];
    __shared__ float sa[128 * 3];
    __shared__ float sd[128];
    int bm = blockIdx.x * 128;
    int t = threadIdx.x;
    int wave = t >> 6, lane = t & 63, quad = lane >> 4, l16 = lane & 15;
    int wm = (wave >> 2) * 64;
    int wn = (wave & 3) * 64;
    f32x4 acc[4][4] = {};

    for (int j = t; j < 3 * C1; j += 512) sW1[j] = W1[j];
    if (t < C1) sb1[t] = b1[t];
    if (t < 128 * 3) {
        int r = bm + t / 3; if (r > M - 1) r = M - 1;
        sa[t] = aggx[r * 3 + (t % 3)];
    }
    if (t < 128) {
        int r = bm + t; if (r > M - 1) r = M - 1;
        sd[t] = dis[r];
    }
    __syncthreads();

    int ar = t >> 2, ak = (t & 3) * 8;
    int br = t >> 1, bk = (t & 1) * 16;
    float a0 = sa[ar * 3 + 0], a1 = sa[ar * 3 + 1], a2 = sa[ar * 3 + 2];
    float drow = sd[ar];

    for (int k0 = 0; k0 < C1; k0 += 32) {
#pragma unroll
        for (int j = 0; j < 8; ++j) {
            int k = k0 + ak + j;
            float v = a0 * sW1[k] + a1 * sW1[C1 + k] + a2 * sW1[2 * C1 + k] + sb1[k];
            As[ar * 32 + ak + j] = f2bf(drow * fmaxf(v, 0.f));
        }
        const short* bptr = Bt + (size_t)br * C1 + bk + k0;
        *(bh8*)&Bs[br * 32 + bk]     = *(const bh8*)bptr;
        *(bh8*)&Bs[br * 32 + bk + 8] = *(const bh8*)(bptr + 8);
        __syncthreads();
        bh8 af[4], bf[4];
#pragma unroll
        for (int mt = 0; mt < 4; ++mt)
            af[mt] = *(const bh8*)&As[(wm + mt * 16 + l16) * 32 + quad * 8];
#pragma unroll
        for (int nt = 0; nt < 4; ++nt)
            bf[nt] = *(const bh8*)&Bs[(wn + nt * 16 + l16) * 32 + quad * 8];
#pragma unroll
        for (int mt = 0; mt < 4; ++mt)
#pragma unroll
            for (int nt = 0; nt < 4; ++nt)
                acc[mt][nt] = __builtin_amdgcn_mfma_f32_16x16x32_bf16(af[mt], bf[nt], acc[mt][nt], 0, 0, 0);
        __syncthreads();
    }

#pragma unroll
    for (int mt = 0; mt < 4; ++mt)
#pragma unroll
        for (int nt = 0; nt < 4; ++nt) {
            int colc = wn + nt * 16 + l16;
#pragma unroll
            for (int r = 0; r < 4; ++r) {
                int rowc = bm + wm + mt * 16 + quad * 4 + r;
                if (rowc < M) Cmat[(size_t)rowc * C2 + colc] = f2fp8(acc[mt][nt][r]);
            }
        }
}

// ------- bf16 MFMA GEMM, full-width N tile, OUTPUT FP8: C[M x BN] = A[M x K] * Bt^T -------

template <int K, int BN>
__global__ __launch_bounds__(512, 4) void gemm_bf16(const short* __restrict__ A,
                                                    const short* __restrict__ Bt,
                                                    unsigned char* __restrict__ Cmat, int M) {
    __shared__ short As[128 * 32];
    __shared__ short Bs[BN * 32];
    constexpr int NT = BN / 64;
    int bm = blockIdx.x * 128;
    int t = threadIdx.x;
    int wave = t >> 6, lane = t & 63, quad = lane >> 4, l16 = lane & 15;
    int wm = (wave >> 2) * 64;
    int wn = (wave & 3) * (BN / 4);
    f32x4 acc[4][NT] = {};

    int ar = t >> 2, ak = (t & 3) * 8;
    int agr = bm + ar; if (agr > M - 1) agr = M - 1;
    const short* aptr = A + (size_t)agr * K + ak;

    for (int k0 = 0; k0 < K; k0 += 32) {
        *(bh8*)&As[ar * 32 + ak] = *(const bh8*)(aptr + k0);
        if constexpr (BN == 256) {
            int br = t >> 1, bk = (t & 1) * 16;
            const short* bptr = Bt + (size_t)br * K + bk + k0;
            *(bh8*)&Bs[br * 32 + bk]     = *(const bh8*)bptr;
            *(bh8*)&Bs[br * 32 + bk + 8] = *(const bh8*)(bptr + 8);
        } else { // BN == 128
            int br = t >> 2, bk = (t & 3) * 8;
            *(bh8*)&Bs[br * 32 + bk] = *(const bh8*)(Bt + (size_t)br * K + bk + k0);
        }
        __syncthreads();
        bh8 af[4], bf[NT];
#pragma unroll
        for (int mt = 0; mt < 4; ++mt)
            af[mt] = *(const bh8*)&As[(wm + mt * 16 + l16) * 32 + quad * 8];
#pragma unroll
        for (int nt = 0; nt < NT; ++nt)
            bf[nt] = *(const bh8*)&Bs[(wn + nt * 16 + l16) * 32 + quad * 8];
#pragma unroll
        for (int mt = 0; mt < 4; ++mt)
#pragma unroll
            for (int nt = 0; nt < NT; ++nt)
                acc[mt][nt] = __builtin_amdgcn_mfma_f32_16x16x32_bf16(af[mt], bf[nt], acc[mt][nt], 0, 0, 0);
        __syncthreads();
    }

#pragma unroll
    for (int mt = 0; mt < 4; ++mt)
#pragma unroll
        for (int nt = 0; nt < NT; ++nt) {
            int colc = wn + nt * 16 + l16;
#pragma unroll
            for (int r = 0; r < 4; ++r) {
                int rowc = bm + wm + mt * 16 + quad * 4 + r;
                if (rowc < M) Cmat[(size_t)rowc * BN + colc] = f2fp8(acc[mt][nt][r]);
            }
        }
}

// ---- fp8-message aggregation (pre-scaled by dis[src]); NPB nodes per 128-thread block ----
// m is [N][C] fp8; C/2 threads per node own 2 channels each (packed-pair decode).
// out = [PRESCALE ? dis_i : 1] * relu( dis_i * (m[i] + sum_r m[r]) + bias )

template <int C, int NPB, bool PRESCALE>
__global__ __launch_bounds__(128) void aggregate_ns(const unsigned char* __restrict__ m,
        const int* __restrict__ offsets, const int* __restrict__ csr_src,
        const float* __restrict__ dis, const float* __restrict__ bias,
        short* __restrict__ out) {
    constexpr int TPN = C / 2;
    int i = blockIdx.x * NPB + threadIdx.x / TPN;
    int t = threadIdx.x % TPN;
    if (NPB > 1 && i >= N_NODES) return;
    float di = dis[i];
    const unsigned short* mu = (const unsigned short*)m;
    float2 sf = fp8x2(mu[(size_t)i * TPN + t]); // self term (already dis_i-scaled)
    float acc0 = sf.x, acc1 = sf.y;
    int s = offsets[i], e = offsets[i + 1];
    int p = s;
    for (; p + 8 <= e; p += 8) {
        int r0 = csr_src[p],     r1 = csr_src[p + 1], r2 = csr_src[p + 2], r3 = csr_src[p + 3];
        int r4 = csr_src[p + 4], r5 = csr_src[p + 5], r6 = csr_src[p + 6], r7 = csr_src[p + 7];
        unsigned short u0 = mu[(size_t)r0 * TPN + t];
        unsigned short u1 = mu[(size_t)r1 * TPN + t];
        unsigned short u2 = mu[(size_t)r2 * TPN + t];
        unsigned short u3 = mu[(size_t)r3 * TPN + t];
        unsigned short u4 = mu[(size_t)r4 * TPN + t];
        unsigned short u5 = mu[(size_t)r5 * TPN + t];
        unsigned short u6 = mu[(size_t)r6 * TPN + t];
        unsigned short u7 = mu[(size_t)r7 * TPN + t];
        float2 f0 = fp8x2(u0), f1 = fp8x2(u1), f2 = fp8x2(u2), f3 = fp8x2(u3);
        float2 f4 = fp8x2(u4), f5 = fp8x2(u5), f6 = fp8x2(u6), f7 = fp8x2(u7);
        acc0 += f0.x + f1.x + f2.x + f3.x + f4.x + f5.x + f6.x + f7.x;
        acc1 += f0.y + f1.y + f2.y + f3.y + f4.y + f5.y + f6.y + f7.y;
    }
    for (; p < e; ++p) {
        int r = csr_src[p];
        float2 f = fp8x2(mu[(size_t)r * TPN + t]);
        acc0 += f.x;
        acc1 += f.y;
    }
    acc0 = fmaxf(di * acc0 + bias[2 * t], 0.f);
    acc1 = fmaxf(di * acc1 + bias[2 * t + 1], 0.f);
    if (PRESCALE) { acc0 *= di; acc1 *= di; }
    ((unsigned int*)out)[(size_t)i * TPN + t] = packbf(acc0, acc1);
}

// ---------------- two-stage mean pool: per-(graph,split) partial sums, few atomics ----------------

__global__ void pool_partial(const short* __restrict__ h3, const int* __restrict__ batch,
                             float* __restrict__ pooled) {
    int g = blockIdx.x, sp = blockIdx.y;
    int t = threadIdx.x; // 64 threads, 2 channels each (C3=128)
    __shared__ int seg[2];
    if (t < 2) {
        int target = g + t;
        int lo = 0, hi = N_NODES;
        while (lo < hi) { int mid = (lo + hi) >> 1; if (batch[mid] < target) lo = mid + 1; else hi = mid; }
        seg[t] = lo;
    }
    __syncthreads();
    int start = seg[0], end = seg[1];
    int len = end - start;
    int chunk = (len + PSPLIT - 1) / PSPLIT;
    int a = start + sp * chunk;
    int b = a + chunk; if (b > end) b = end;
    if (a >= b) return;
    const unsigned int* hu = (const unsigned int*)h3;
    float s0 = 0.f, s1 = 0.f;
    int i = a;
    for (; i + 4 <= b; i += 4) {
        unsigned int u0 = hu[(size_t)(i + 0) * (C3 / 2) + t];
        unsigned int u1 = hu[(size_t)(i + 1) * (C3 / 2) + t];
        unsigned int u2 = hu[(size_t)(i + 2) * (C3 / 2) + t];
        unsigned int u3 = hu[(size_t)(i + 3) * (C3 / 2) + t];
        s0 += bflo(u0) + bflo(u1) + bflo(u2) + bflo(u3);
        s1 += bfhi(u0) + bfhi(u1) + bfhi(u2) + bfhi(u3);
    }
    for (; i < b; ++i) {
        unsigned int u = hu[(size_t)i * (C3 / 2) + t];
        s0 += bflo(u);
        s1 += bfhi(u);
    }
    atomicAdd(&pooled[g * C3 + 2 * t], s0);
    atomicAdd(&pooled[g * C3 + 2 * t + 1], s1);
}

// ---------------- head: mean-divide + linear + log_softmax ----------------

__global__ void finalize_head(const float* __restrict__ pooled, const int* __restrict__ batch,
                              const float* __restrict__ Wc, const float* __restrict__ bc,
                              float* __restrict__ outp) {
    int g = blockIdx.x;
    int t = threadIdx.x; // 128 threads = C3
    __shared__ int seg[2];
    if (t < 2) {
        int target = g + t;
        int lo = 0, hi = N_NODES;
        while (lo < hi) { int mid = (lo + hi) >> 1; if (batch[mid] < target) lo = mid + 1; else hi = mid; }
        seg[t] = lo;
    }
    __syncthreads();
    float cnt = (float)(seg[1] - seg[0]);
    float pv = pooled[(size_t)g * C3 + t] / fmaxf(cnt, 1.f);
    float p0 = pv * Wc[t * 2 + 0];
    float p1 = pv * Wc[t * 2 + 1];
#pragma unroll
    for (int o = 32; o > 0; o >>= 1) {
        p0 += __shfl_down(p0, o);
        p1 += __shfl_down(p1, o);
    }
    __shared__ float r0[2], r1[2];
    int wid = t >> 6, lane = t & 63;
    if (lane == 0) { r0[wid] = p0; r1[wid] = p1; }
    __syncthreads();
    if (t == 0) {
        float l0 = r0[0] + r0[1] + bc[0];
        float l1 = r1[0] + r1[1] + bc[1];
        float mx = fmaxf(l0, l1);
        float lse = mx + logf(expf(l0 - mx) + expf(l1 - mx));
        outp[g * 2 + 0] = l0 - lse;
        outp[g * 2 + 1] = l1 - lse;
    }
}

// ---------------- launch ----------------

extern "C" void kernel_launch(void* const* d_in, const int* in_sizes, int n_in,
                              void* d_out, int out_size, void* d_ws, size_t ws_size,
                              hipStream_t stream) {
    const float* x = (const float*)d_in[0];
    const float* W1 = (const float*)d_in[1];
    const float* b1 = (const float*)d_in[2];
    const float* W2 = (const float*)d_in[3];
    const float* b2 = (const float*)d_in[4];
    const float* W3 = (const float*)d_in[5];
    const float* b3 = (const float*)d_in[6];
    const float* Wc = (const float*)d_in[7];
    const float* bc = (const float*)d_in[8];
    const int* ei = (const int*)d_in[9];
    const int* batch = (const int*)d_in[10];
    const int* row = ei;
    const int* col = ei + N_EDGES;
    float* out = (float*)d_out;

    char* ws = (char*)d_ws;
    size_t off = 0;
    auto alloc = [&](size_t bytes) -> void* {
        off = (off + 255) & ~(size_t)255;
        void* p = ws + off;
        off += bytes;
        return p;
    };

    int* counts = (int*)alloc((size_t)N_NODES * 4);
    int* offsets = (int*)alloc((size_t)(N_NODES + 1) * 4);
    int* cursor = (int*)alloc((size_t)N_NODES * 4);
    int* chunksums = (int*)alloc(256 * 4);
    float* dis = (float*)alloc((size_t)N_NODES * 4);
    float4* xd = (float4*)alloc((size_t)N_NODES * 16);
    int* csr_src = (int*)alloc((size_t)N_EDGES * 4);
    float* aggx = (float*)alloc((size_t)N_NODES * 3 * 4);
    short* W2t = (short*)alloc((size_t)C1 * C2 * 2);   // [C2][C1] bf16
    short* W3t = (short*)alloc((size_t)C2 * C3 * 2);   // [C3][C2] bf16
    unsigned char* m2 = (unsigned char*)alloc((size_t)N_NODES * C2); // fp8
    short* h2 = (short*)alloc((size_t)N_NODES * C2 * 2);             // bf16
    unsigned char* m3 = (unsigned char*)alloc((size_t)N_NODES * C3); // fp8
    short* h3 = (short*)alloc((size_t)N_NODES * C3 * 2);             // bf16
    float* pooled = (float*)alloc((size_t)NGRAPH * C3 * 4);

    hipMemsetAsync(counts, 0, (size_t)N_NODES * 4, stream);
    hipMemsetAsync(pooled, 0, (size_t)NGRAPH * C3 * 4, stream);
    int nechunks = (N_EDGES + 255) / 256;
    count_edges<<<nechunks * NRANGE, 256, 0, stream>>>(col, counts);
    int nchunks = (N_NODES + 255) / 256;
    scan_chunks<<<nchunks, 256, 0, stream>>>(counts, x, offsets, chunksums, dis, xd);
    scan_sums<<<1, 256, 0, stream>>>(chunksums, nchunks);
    finalize_offsets<<<(N_NODES + 255) / 256, 256, 0, stream>>>(offsets, chunksums, cursor);
    scatter_edges<<<nechunks * NRANGE, 256, 0, stream>>>(row, col, cursor, csr_src);

    prep_weights<<<(C1 * C2 + C2 * C3 + 255) / 256, 256, 0, stream>>>(W2, W3, W2t, W3t);

    agg_feat3<<<(N_NODES + 15) / 16, 256, 0, stream>>>(xd, offsets, csr_src, aggx);

    gemm_l1<<<(N_NODES + 127) / 128, 512, 0, stream>>>(aggx, W1, b1, dis, W2t, m2, N_NODES);
    aggregate_ns<C2, 1, true><<<N_NODES, 128, 0, stream>>>(m2, offsets, csr_src, dis, b2, h2);

    gemm_bf16<C2, C3><<<(N_NODES + 127) / 128, 512, 0, stream>>>(h2, W3t, m3, N_NODES);
    aggregate_ns<C3, 2, false><<<(N_NODES + 1) / 2, 128, 0, stream>>>(m3, offsets, csr_src, dis, b3, h3);

    dim3 gp(NGRAPH, PSPLIT);
    pool_partial<<<gp, C3 / 2, 0, stream>>>(h3, batch, pooled);
    finalize_head<<<NGRAPH, C3, 0, stream>>>(pooled, batch, Wc, bc, out);
}

// Round 16
// 298.523 us; speedup vs baseline: 1.0751x; 1.0751x over previous
//
#include <hip/hip_runtime.h>
#include <hip/hip_bf16.h>
#include <hip/hip_fp8.h>
#include <math.h>

#define N_NODES 50000
#define N_EDGES 800000
#define NFEAT 3
#define C1 512
#define C2 256
#define C3 128
#define NGRAPH 100
#define NCLS 2
#define PSPLIT 8
#define NRANGE 8
#define RANGE_SZ 6250  // N_NODES / NRANGE

typedef short bh8 __attribute__((ext_vector_type(8)));   // 8 bf16 bit-patterns (4 VGPRs)
typedef float f32x4 __attribute__((ext_vector_type(4))); // MFMA accumulator

__device__ __forceinline__ short f2bf(float x) {
    __hip_bfloat16 h = __float2bfloat16(x);
    return *reinterpret_cast<short*>(&h);
}
__device__ __forceinline__ float bflo(unsigned int u) { return __uint_as_float(u << 16); }
__device__ __forceinline__ float bfhi(unsigned int u) { return __uint_as_float(u & 0xffff0000u); }
__device__ __forceinline__ unsigned int packbf(float a, float b) {
    return (unsigned int)(unsigned short)f2bf(a) | ((unsigned int)(unsigned short)f2bf(b) << 16);
}
// OCP e4m3 fp8 encode; packed-pair decode (HW v_cvt_pk_f32_fp8 on gfx950)
__device__ __forceinline__ unsigned char f2fp8(float x) {
    __hip_fp8_e4m3 q(x);
    return (unsigned char)q.__x;
}
__device__ __forceinline__ float2 fp8x2(unsigned short u) {
    __hip_fp8x2_e4m3 q; q.__x = u; return (float2)q;
}

// ---------------- degree count, col-range partitioned (XCD-local atomics) ----------------

__global__ void count_edges(const int* __restrict__ col, int* __restrict__ counts) {
    int range = blockIdx.x & (NRANGE - 1);
    int e = (blockIdx.x >> 3) * 256 + threadIdx.x;
    if (e < N_EDGES) {
        int c = col[e];
        int lo = range * RANGE_SZ;
        if (c >= lo && c < lo + RANGE_SZ) atomicAdd(&counts[c], 1);
    }
}

// ------- CSR build: scan (fused dis + packed xd={x,dis}) + partitioned scatter -------

__global__ void scan_chunks(const int* __restrict__ counts, const float* __restrict__ x,
                            int* __restrict__ offsets, int* __restrict__ chunksums,
                            float* __restrict__ dis, float4* __restrict__ xd) {
    __shared__ int s[256];
    int b = blockIdx.x, t = threadIdx.x;
    int i = b * 256 + t;
    int v = (i < N_NODES) ? counts[i] : 0;
    if (i < N_NODES) {
        float d = rsqrtf((float)(v + 1)); // +1 self loop
        dis[i] = d;
        xd[i] = make_float4(x[i * 3 + 0], x[i * 3 + 1], x[i * 3 + 2], d);
    }
    s[t] = v;
    __syncthreads();
    for (int d = 1; d < 256; d <<= 1) {
        int add = (t >= d) ? s[t - d] : 0;
        __syncthreads();
        s[t] += add;
        __syncthreads();
    }
    if (i < N_NODES) offsets[i + 1] = s[t];
    if (t == 255) chunksums[b] = s[255];
}

__global__ void scan_sums(int* __restrict__ chunksums, int nchunks) {
    __shared__ int s[256];
    int t = threadIdx.x;
    int v = (t < nchunks) ? chunksums[t] : 0;
    s[t] = v;
    __syncthreads();
    for (int d = 1; d < 256; d <<= 1) {
        int add = (t >= d) ? s[t - d] : 0;
        __syncthreads();
        s[t] += add;
        __syncthreads();
    }
    if (t < nchunks) chunksums[t] = (t == 0) ? 0 : s[t - 1];
}

// also initializes cursor[] = final offsets (no separate init kernel)
__global__ void finalize_offsets(int* __restrict__ offsets, const int* __restrict__ chunkoffs,
                                 int* __restrict__ cursor) {
    int i = blockIdx.x * blockDim.x + threadIdx.x;
    if (i < N_NODES) {
        int v = offsets[i + 1] + chunkoffs[i / 256];
        offsets[i + 1] = v;
        if (i + 1 < N_NODES) cursor[i + 1] = v;
    }
    if (i == 0) { offsets[0] = 0; cursor[0] = 0; }
}

__global__ void scatter_edges(const int* __restrict__ rowi, const int* __restrict__ coli,
                              int* __restrict__ cursor, int* __restrict__ csr_src) {
    int range = blockIdx.x & (NRANGE - 1);
    int e = (blockIdx.x >> 3) * 256 + threadIdx.x;
    if (e < N_EDGES) {
        int c = coli[e];
        int lo = range * RANGE_SZ;
        if (c >= lo && c < lo + RANGE_SZ) {
            int p = atomicAdd(&cursor[c], 1);
            csr_src[p] = rowi[e];
        }
    }
}

// ---------------- weight transpose + bf16 cast (both layers in one kernel) ----------------

__global__ void prep_weights(const float* __restrict__ W2, const float* __restrict__ W3,
                             short* __restrict__ W2t, short* __restrict__ W3t) {
    int idx = blockIdx.x * 256 + threadIdx.x;
    if (idx < C1 * C2) {
        int n = idx / C1, k = idx % C1;
        W2t[idx] = f2bf(W2[k * C2 + n]);
    } else if (idx < C1 * C2 + C2 * C3) {
        int j = idx - C1 * C2;
        int n = j / C2, k = j % C2;
        W3t[j] = f2bf(W3[k * C3 + n]);
    }
}

// ------- layer-1 feature aggregate: 16 lanes per node, shuffle-reduced -------
// xd[i] = {x0,x1,x2,dis}; aggx[i] = dis_i * ( dis_i*x[i] + sum_r dis_r*x[r] )

__global__ __launch_bounds__(256) void agg_feat3(const float4* __restrict__ xd,
                                                 const int* __restrict__ offsets,
                                                 const int* __restrict__ csr_src,
                                                 float* __restrict__ aggx) {
    int t = threadIdx.x;
    int l = t & 15;            // lane within 16-lane group
    int i = blockIdx.x * 16 + (t >> 4);
    if (i >= N_NODES) return;
    int s = offsets[i], e = offsets[i + 1];
    float a0 = 0.f, a1 = 0.f, a2 = 0.f;
    for (int p = s + l; p < e; p += 16) {
        int r = csr_src[p];
        float4 v = xd[r];
        a0 += v.w * v.x;
        a1 += v.w * v.y;
        a2 += v.w * v.z;
    }
#pragma unroll
    for (int m = 1; m < 16; m <<= 1) {
        a0 += __shfl_xor(a0, m);
        a1 += __shfl_xor(a1, m);
        a2 += __shfl_xor(a2, m);
    }
    if (l == 0) {
        float4 self = xd[i];
        float di = self.w;
        a0 += di * self.x; a1 += di * self.y; a2 += di * self.z;
        aggx[i * 3 + 0] = di * a0;
        aggx[i * 3 + 1] = di * a1;
        aggx[i * 3 + 2] = di * a2;
    }
}

// ---- FUSED layer1 + GEMM2: m2[M x C2] = (di*relu(aggx@W1+b1)) @ W2t^T, OUTPUT FP8 ----

__global__ __launch_bounds__(512, 4) void gemm_l1(const float* __restrict__ aggx,
                                                  const float* __restrict__ W1,
                                                  const float* __restrict__ b1,
                                                  const float* __restrict__ dis,
                                                  const short* __restrict__ Bt,
                                                  unsigned char* __restrict__ Cmat, int M) {
    __shared__ short As[128 * 32];
    __shared__ short Bs[C2 * 32];
    __shared__ float sW1[3 * C1];
    __shared__ float sb1[C1];
    __shared__ float sa[128 * 3];
    __shared__ float sd[128];
    int bm = blockIdx.x * 128;
    int t = threadIdx.x;
    int wave = t >> 6, lane = t & 63, quad = lane >> 4, l16 = lane & 15;
    int wm = (wave >> 2) * 64;
    int wn = (wave & 3) * 64;
    f32x4 acc[4][4] = {};

    for (int j = t; j < 3 * C1; j += 512) sW1[j] = W1[j];
    if (t < C1) sb1[t] = b1[t];
    if (t < 128 * 3) {
        int r = bm + t / 3; if (r > M - 1) r = M - 1;
        sa[t] = aggx[r * 3 + (t % 3)];
    }
    if (t < 128) {
        int r = bm + t; if (r > M - 1) r = M - 1;
        sd[t] = dis[r];
    }
    __syncthreads();

    int ar = t >> 2, ak = (t & 3) * 8;
    int br = t >> 1, bk = (t & 1) * 16;
    float a0 = sa[ar * 3 + 0], a1 = sa[ar * 3 + 1], a2 = sa[ar * 3 + 2];
    float drow = sd[ar];

    for (int k0 = 0; k0 < C1; k0 += 32) {
#pragma unroll
        for (int j = 0; j < 8; ++j) {
            int k = k0 + ak + j;
            float v = a0 * sW1[k] + a1 * sW1[C1 + k] + a2 * sW1[2 * C1 + k] + sb1[k];
            As[ar * 32 + ak + j] = f2bf(drow * fmaxf(v, 0.f));
        }
        const short* bptr = Bt + (size_t)br * C1 + bk + k0;
        *(bh8*)&Bs[br * 32 + bk]     = *(const bh8*)bptr;
        *(bh8*)&Bs[br * 32 + bk + 8] = *(const bh8*)(bptr + 8);
        __syncthreads();
        bh8 af[4], bf[4];
#pragma unroll
        for (int mt = 0; mt < 4; ++mt)
            af[mt] = *(const bh8*)&As[(wm + mt * 16 + l16) * 32 + quad * 8];
#pragma unroll
        for (int nt = 0; nt < 4; ++nt)
            bf[nt] = *(const bh8*)&Bs[(wn + nt * 16 + l16) * 32 + quad * 8];
#pragma unroll
        for (int mt = 0; mt < 4; ++mt)
#pragma unroll
            for (int nt = 0; nt < 4; ++nt)
                acc[mt][nt] = __builtin_amdgcn_mfma_f32_16x16x32_bf16(af[mt], bf[nt], acc[mt][nt], 0, 0, 0);
        __syncthreads();
    }

#pragma unroll
    for (int mt = 0; mt < 4; ++mt)
#pragma unroll
        for (int nt = 0; nt < 4; ++nt) {
            int colc = wn + nt * 16 + l16;
#pragma unroll
            for (int r = 0; r < 4; ++r) {
                int rowc = bm + wm + mt * 16 + quad * 4 + r;
                if (rowc < M) Cmat[(size_t)rowc * C2 + colc] = f2fp8(acc[mt][nt][r]);
            }
        }
}

// ------- bf16 MFMA GEMM, full-width N tile, OUTPUT FP8: C[M x BN] = A[M x K] * Bt^T -------

template <int K, int BN>
__global__ __launch_bounds__(512, 4) void gemm_bf16(const short* __restrict__ A,
                                                    const short* __restrict__ Bt,
                                                    unsigned char* __restrict__ Cmat, int M) {
    __shared__ short As[128 * 32];
    __shared__ short Bs[BN * 32];
    constexpr int NT = BN / 64;
    int bm = blockIdx.x * 128;
    int t = threadIdx.x;
    int wave = t >> 6, lane = t & 63, quad = lane >> 4, l16 = lane & 15;
    int wm = (wave >> 2) * 64;
    int wn = (wave & 3) * (BN / 4);
    f32x4 acc[4][NT] = {};

    int ar = t >> 2, ak = (t & 3) * 8;
    int agr = bm + ar; if (agr > M - 1) agr = M - 1;
    const short* aptr = A + (size_t)agr * K + ak;

    for (int k0 = 0; k0 < K; k0 += 32) {
        *(bh8*)&As[ar * 32 + ak] = *(const bh8*)(aptr + k0);
        if constexpr (BN == 256) {
            int br = t >> 1, bk = (t & 1) * 16;
            const short* bptr = Bt + (size_t)br * K + bk + k0;
            *(bh8*)&Bs[br * 32 + bk]     = *(const bh8*)bptr;
            *(bh8*)&Bs[br * 32 + bk + 8] = *(const bh8*)(bptr + 8);
        } else { // BN == 128
            int br = t >> 2, bk = (t & 3) * 8;
            *(bh8*)&Bs[br * 32 + bk] = *(const bh8*)(Bt + (size_t)br * K + bk + k0);
        }
        __syncthreads();
        bh8 af[4], bf[NT];
#pragma unroll
        for (int mt = 0; mt < 4; ++mt)
            af[mt] = *(const bh8*)&As[(wm + mt * 16 + l16) * 32 + quad * 8];
#pragma unroll
        for (int nt = 0; nt < NT; ++nt)
            bf[nt] = *(const bh8*)&Bs[(wn + nt * 16 + l16) * 32 + quad * 8];
#pragma unroll
        for (int mt = 0; mt < 4; ++mt)
#pragma unroll
            for (int nt = 0; nt < NT; ++nt)
                acc[mt][nt] = __builtin_amdgcn_mfma_f32_16x16x32_bf16(af[mt], bf[nt], acc[mt][nt], 0, 0, 0);
        __syncthreads();
    }

#pragma unroll
    for (int mt = 0; mt < 4; ++mt)
#pragma unroll
        for (int nt = 0; nt < NT; ++nt) {
            int colc = wn + nt * 16 + l16;
#pragma unroll
            for (int r = 0; r < 4; ++r) {
                int rowc = bm + wm + mt * 16 + quad * 4 + r;
                if (rowc < M) Cmat[(size_t)rowc * BN + colc] = f2fp8(acc[mt][nt][r]);
            }
        }
}

// ---- fp8-message aggregation (pre-scaled by dis[src]); block-per-node, x8 unroll ----
// i = blockIdx.x MUST stay syntactically uniform: the compiler then emits scalar
// s_loads for offsets/dis and the csr_src index stream (round-15 NPB templating
// broke this and cost 25%). m is [N][C] fp8; thread t owns channels 2t,2t+1.

template <int C, bool PRESCALE>
__global__ void aggregate_ns(const unsigned char* __restrict__ m, const int* __restrict__ offsets,
                             const int* __restrict__ csr_src, const float* __restrict__ dis,
                             const float* __restrict__ bias, short* __restrict__ out) {
    int i = blockIdx.x;
    int t = threadIdx.x; // C/2 threads, 2 channels each
    float di = dis[i];
    const unsigned short* mu = (const unsigned short*)m;
    float2 sf = fp8x2(mu[(size_t)i * (C / 2) + t]); // self term (already dis_i-scaled)
    float acc0 = sf.x, acc1 = sf.y;
    int s = offsets[i], e = offsets[i + 1];
    int p = s;
    for (; p + 8 <= e; p += 8) {
        int r0 = csr_src[p],     r1 = csr_src[p + 1], r2 = csr_src[p + 2], r3 = csr_src[p + 3];
        int r4 = csr_src[p + 4], r5 = csr_src[p + 5], r6 = csr_src[p + 6], r7 = csr_src[p + 7];
        unsigned short u0 = mu[(size_t)r0 * (C / 2) + t];
        unsigned short u1 = mu[(size_t)r1 * (C / 2) + t];
        unsigned short u2 = mu[(size_t)r2 * (C / 2) + t];
        unsigned short u3 = mu[(size_t)r3 * (C / 2) + t];
        unsigned short u4 = mu[(size_t)r4 * (C / 2) + t];
        unsigned short u5 = mu[(size_t)r5 * (C / 2) + t];
        unsigned short u6 = mu[(size_t)r6 * (C / 2) + t];
        unsigned short u7 = mu[(size_t)r7 * (C / 2) + t];
        float2 f0 = fp8x2(u0), f1 = fp8x2(u1), f2 = fp8x2(u2), f3 = fp8x2(u3);
        float2 f4 = fp8x2(u4), f5 = fp8x2(u5), f6 = fp8x2(u6), f7 = fp8x2(u7);
        acc0 += f0.x + f1.x + f2.x + f3.x + f4.x + f5.x + f6.x + f7.x;
        acc1 += f0.y + f1.y + f2.y + f3.y + f4.y + f5.y + f6.y + f7.y;
    }
    for (; p < e; ++p) {
        int r = csr_src[p];
        float2 f = fp8x2(mu[(size_t)r * (C / 2) + t]);
        acc0 += f.x;
        acc1 += f.y;
    }
    acc0 = fmaxf(di * acc0 + bias[2 * t], 0.f);
    acc1 = fmaxf(di * acc1 + bias[2 * t + 1], 0.f);
    if (PRESCALE) { acc0 *= di; acc1 *= di; }
    ((unsigned int*)out)[(size_t)i * (C / 2) + t] = packbf(acc0, acc1);
}

// ---------------- two-stage mean pool: per-(graph,split) partial sums, few atomics ----------------

__global__ void pool_partial(const short* __restrict__ h3, const int* __restrict__ batch,
                             float* __restrict__ pooled) {
    int g = blockIdx.x, sp = blockIdx.y;
    int t = threadIdx.x; // 64 threads, 2 channels each (C3=128)
    __shared__ int seg[2];
    if (t < 2) {
        int target = g + t;
        int lo = 0, hi = N_NODES;
        while (lo < hi) { int mid = (lo + hi) >> 1; if (batch[mid] < target) lo = mid + 1; else hi = mid; }
        seg[t] = lo;
    }
    __syncthreads();
    int start = seg[0], end = seg[1];
    int len = end - start;
    int chunk = (len + PSPLIT - 1) / PSPLIT;
    int a = start + sp * chunk;
    int b = a + chunk; if (b > end) b = end;
    if (a >= b) return;
    const unsigned int* hu = (const unsigned int*)h3;
    float s0 = 0.f, s1 = 0.f;
    int i = a;
    for (; i + 4 <= b; i += 4) {
        unsigned int u0 = hu[(size_t)(i + 0) * (C3 / 2) + t];
        unsigned int u1 = hu[(size_t)(i + 1) * (C3 / 2) + t];
        unsigned int u2 = hu[(size_t)(i + 2) * (C3 / 2) + t];
        unsigned int u3 = hu[(size_t)(i + 3) * (C3 / 2) + t];
        s0 += bflo(u0) + bflo(u1) + bflo(u2) + bflo(u3);
        s1 += bfhi(u0) + bfhi(u1) + bfhi(u2) + bfhi(u3);
    }
    for (; i < b; ++i) {
        unsigned int u = hu[(size_t)i * (C3 / 2) + t];
        s0 += bflo(u);
        s1 += bfhi(u);
    }
    atomicAdd(&pooled[g * C3 + 2 * t], s0);
    atomicAdd(&pooled[g * C3 + 2 * t + 1], s1);
}

// ---------------- head: mean-divide + linear + log_softmax ----------------

__global__ void finalize_head(const float* __restrict__ pooled, const int* __restrict__ batch,
                              const float* __restrict__ Wc, const float* __restrict__ bc,
                              float* __restrict__ outp) {
    int g = blockIdx.x;
    int t = threadIdx.x; // 128 threads = C3
    __shared__ int seg[2];
    if (t < 2) {
        int target = g + t;
        int lo = 0, hi = N_NODES;
        while (lo < hi) { int mid = (lo + hi) >> 1; if (batch[mid] < target) lo = mid + 1; else hi = mid; }
        seg[t] = lo;
    }
    __syncthreads();
    float cnt = (float)(seg[1] - seg[0]);
    float pv = pooled[(size_t)g * C3 + t] / fmaxf(cnt, 1.f);
    float p0 = pv * Wc[t * 2 + 0];
    float p1 = pv * Wc[t * 2 + 1];
#pragma unroll
    for (int o = 32; o > 0; o >>= 1) {
        p0 += __shfl_down(p0, o);
        p1 += __shfl_down(p1, o);
    }
    __shared__ float r0[2], r1[2];
    int wid = t >> 6, lane = t & 63;
    if (lane == 0) { r0[wid] = p0; r1[wid] = p1; }
    __syncthreads();
    if (t == 0) {
        float l0 = r0[0] + r0[1] + bc[0];
        float l1 = r1[0] + r1[1] + bc[1];
        float mx = fmaxf(l0, l1);
        float lse = mx + logf(expf(l0 - mx) + expf(l1 - mx));
        outp[g * 2 + 0] = l0 - lse;
        outp[g * 2 + 1] = l1 - lse;
    }
}

// ---------------- launch ----------------

extern "C" void kernel_launch(void* const* d_in, const int* in_sizes, int n_in,
                              void* d_out, int out_size, void* d_ws, size_t ws_size,
                              hipStream_t stream) {
    const float* x = (const float*)d_in[0];
    const float* W1 = (const float*)d_in[1];
    const float* b1 = (const float*)d_in[2];
    const float* W2 = (const float*)d_in[3];
    const float* b2 = (const float*)d_in[4];
    const float* W3 = (const float*)d_in[5];
    const float* b3 = (const float*)d_in[6];
    const float* Wc = (const float*)d_in[7];
    const float* bc = (const float*)d_in[8];
    const int* ei = (const int*)d_in[9];
    const int* batch = (const int*)d_in[10];
    const int* row = ei;
    const int* col = ei + N_EDGES;
    float* out = (float*)d_out;

    char* ws = (char*)d_ws;
    size_t off = 0;
    auto alloc = [&](size_t bytes) -> void* {
        off = (off + 255) & ~(size_t)255;
        void* p = ws + off;
        off += bytes;
        return p;
    };

    int* counts = (int*)alloc((size_t)N_NODES * 4);
    int* offsets = (int*)alloc((size_t)(N_NODES + 1) * 4);
    int* cursor = (int*)alloc((size_t)N_NODES * 4);
    int* chunksums = (int*)alloc(256 * 4);
    float* dis = (float*)alloc((size_t)N_NODES * 4);
    float4* xd = (float4*)alloc((size_t)N_NODES * 16);
    int* csr_src = (int*)alloc((size_t)N_EDGES * 4);
    float* aggx = (float*)alloc((size_t)N_NODES * 3 * 4);
    short* W2t = (short*)alloc((size_t)C1 * C2 * 2);   // [C2][C1] bf16
    short* W3t = (short*)alloc((size_t)C2 * C3 * 2);   // [C3][C2] bf16
    unsigned char* m2 = (unsigned char*)alloc((size_t)N_NODES * C2); // fp8
    short* h2 = (short*)alloc((size_t)N_NODES * C2 * 2);             // bf16
    unsigned char* m3 = (unsigned char*)alloc((size_t)N_NODES * C3); // fp8
    short* h3 = (short*)alloc((size_t)N_NODES * C3 * 2);             // bf16
    float* pooled = (float*)alloc((size_t)NGRAPH * C3 * 4);

    hipMemsetAsync(counts, 0, (size_t)N_NODES * 4, stream);
    hipMemsetAsync(pooled, 0, (size_t)NGRAPH * C3 * 4, stream);
    int nechunks = (N_EDGES + 255) / 256;
    count_edges<<<nechunks * NRANGE, 256, 0, stream>>>(col, counts);
    int nchunks = (N_NODES + 255) / 256;
    scan_chunks<<<nchunks, 256, 0, stream>>>(counts, x, offsets, chunksums, dis, xd);
    scan_sums<<<1, 256, 0, stream>>>(chunksums, nchunks);
    finalize_offsets<<<(N_NODES + 255) / 256, 256, 0, stream>>>(offsets, chunksums, cursor);
    scatter_edges<<<nechunks * NRANGE, 256, 0, stream>>>(row, col, cursor, csr_src);

    prep_weights<<<(C1 * C2 + C2 * C3 + 255) / 256, 256, 0, stream>>>(W2, W3, W2t, W3t);

    agg_feat3<<<(N_NODES + 15) / 16, 256, 0, stream>>>(xd, offsets, csr_src, aggx);

    gemm_l1<<<(N_NODES + 127) / 128, 512, 0, stream>>>(aggx, W1, b1, dis, W2t, m2, N_NODES);
    aggregate_ns<C2, true><<<N_NODES, C2 / 2, 0, stream>>>(m2, offsets, csr_src, dis, b2, h2);

    gemm_bf16<C2, C3><<<(N_NODES + 127) / 128, 512, 0, stream>>>(h2, W3t, m3, N_NODES);
    aggregate_ns<C3, false><<<N_NODES, C3 / 2, 0, stream>>>(m3, offsets, csr_src, dis, b3, h3);

    dim3 gp(NGRAPH, PSPLIT);
    pool_partial<<<gp, C3 / 2, 0, stream>>>(h3, batch, pooled);
    finalize_head<<<NGRAPH, C3, 0, stream>>>(pooled, batch, Wc, bc, out);
}